// Round 11
// baseline (132.551 us; speedup 1.0000x reference)
//
#include <hip/hip_runtime.h>
#include <hip/hip_bf16.h>

// Causal attention, B=2 NH=16 T=2048 D=64, fp32 I/O.
// R11: register-resident flash. K and V^T MFMA fragments are DIRECT global
// b128 loads with one-step register prefetch (ping-pong via 2x-unrolled
// loop) — no K/V LDS staging, no barriers in the k-loop. LDS only for the
// wave-private P round-trip + end-combine dump areas. R10's uniform
// strip-pairing (block = heavy iq=31-m + light iq=m, 66 tiles over 4 waves
// as 17/17/16/16) and in-LDS combine retained; parked heavy partials are
// dumped to their LDS area at switch time (saves regs).
// DS traffic/unit: 24 KB (R10) -> 8 KB (P only). VALU (exp2) becomes the
// binding pipe.

typedef __bf16 bf16;
typedef __bf16 bf16x4 __attribute__((ext_vector_type(4)));
typedef __bf16 bf16x8 __attribute__((ext_vector_type(8)));
typedef float floatx4 __attribute__((ext_vector_type(4)));

#define T_SEQ 2048
#define DH 64
#define TKS 32
#define BHN 32
#define CEXP 0.18033688011112042f  // (1/sqrt(64)) * log2(e)

// ---------------- fused prepass (R9/R10's, unchanged) ----------------
__global__ __launch_bounds__(256) void prep(const float* __restrict__ K,
                                            const float* __restrict__ V,
                                            bf16* __restrict__ Kb,
                                            bf16* __restrict__ Vt) {
    const int bid = (int)blockIdx.x;
    const int tid = (int)threadIdx.x;
    if (bid < 512) {
        size_t i = ((size_t)bid * 256 + tid) * 8;
        #pragma unroll
        for (int it = 0; it < 4; ++it) {
            float4 a = *(const float4*)(K + i + 0);
            float4 b = *(const float4*)(K + i + 4);
            bf16x8 o;
            o[0]=(bf16)a.x; o[1]=(bf16)a.y; o[2]=(bf16)a.z; o[3]=(bf16)a.w;
            o[4]=(bf16)b.x; o[5]=(bf16)b.y; o[6]=(bf16)b.z; o[7]=(bf16)b.w;
            *(bf16x8*)(Kb + i) = o;
            i += (size_t)512 * 256 * 8;
        }
        return;
    }
    __shared__ bf16 tile[2][64][72];
    const int vb = bid - 512;
    const int bh = vb & (BHN - 1);
    const int tp = (vb >> 5) * 128;
    #pragma unroll
    for (int tt = 0; tt < 2; ++tt) {
        const int r = tid >> 2;
        const int c = (tid & 3) * 16;
        const float* s = V + ((size_t)bh * T_SEQ + tp + tt * 64 + r) * DH + c;
        float4 f0 = *(const float4*)(s + 0);
        float4 f1 = *(const float4*)(s + 4);
        float4 f2 = *(const float4*)(s + 8);
        float4 f3 = *(const float4*)(s + 12);
        bf16x8 p0, p1;
        p0[0]=(bf16)f0.x; p0[1]=(bf16)f0.y; p0[2]=(bf16)f0.z; p0[3]=(bf16)f0.w;
        p0[4]=(bf16)f1.x; p0[5]=(bf16)f1.y; p0[6]=(bf16)f1.z; p0[7]=(bf16)f1.w;
        p1[0]=(bf16)f2.x; p1[1]=(bf16)f2.y; p1[2]=(bf16)f2.z; p1[3]=(bf16)f2.w;
        p1[4]=(bf16)f3.x; p1[5]=(bf16)f3.y; p1[6]=(bf16)f3.z; p1[7]=(bf16)f3.w;
        *(bf16x8*)&tile[tt][r][c + 0] = p0;
        *(bf16x8*)&tile[tt][r][c + 8] = p1;
    }
    __syncthreads();
    #pragma unroll
    for (int tt = 0; tt < 2; ++tt) {
        const int d   = tid >> 2;
        const int tch = (tid & 3) * 16;
        bf16x8 o0, o1;
        #pragma unroll
        for (int j = 0; j < 8; ++j) { o0[j] = tile[tt][tch + j][d]; o1[j] = tile[tt][tch + 8 + j][d]; }
        bf16* o = Vt + ((size_t)bh * DH + d) * T_SEQ + tp + tt * 64 + tch;
        *(bf16x8*)(o + 0) = o0;
        *(bf16x8*)(o + 8) = o1;
    }
}

// ---------------- main flash kernel ----------------
// LDS (bf16 elems): dump areas 5 x 4608 @ 0 (o bf16 4096 + l fp32 512),
// P[wave] @ 23040 + wave*2048 ([64 q][32 k], XOR-4 swizzle). Total 62.5 KB.
// MFMA 16x16x32: A[m=l16][k=quad*8+j], B[k=quad*8+j][n=l16], C/D col=l16,row=quad*4+r.
__global__ __launch_bounds__(256, 2)
void fa_fwd(const float* __restrict__ Qg, const bf16* __restrict__ Kb,
            const bf16* __restrict__ Vt, float* __restrict__ Og)
{
    __shared__ __align__(16) bf16 smem[31232];

    const int gid = (int)blockIdx.x;
    const int bh  = gid & (BHN - 1);
    const int m   = gid >> 5;                    // 0..15
    const int B   = 64 - 2 * m;                  // heavy tile count (>=34)
    const int qh  = (31 - m) * 64;
    const int ql  = m * 64;

    const int tid  = (int)threadIdx.x;
    const int wave = tid >> 6;
    const int lane = tid & 63;
    const int quad = lane >> 4;
    const int l16  = lane & 15;
    const int psw  = (l16 >> 1) & 3;

    const int tw0 = (wave < 2) ? wave * 17 : 34 + (wave - 2) * 16;
    const int tw1 = tw0 + ((wave < 2) ? 17 : 16);

    bf16* Pw = smem + 23040 + wave * 2048;

    const bf16* Kbh = Kb + (size_t)bh * (T_SEQ * DH);
    const bf16* Vbh = Vt + (size_t)bh * (DH * T_SEQ);
    const size_t qrb = (size_t)bh * T_SEQ;

    bool heavyNow = (tw0 < B);
    int  qbase    = heavyNow ? qh : ql;
    bool hasPark  = false;

    // ---- Q as B-fragments: B[k=quad*8+j][n=l16], 4 nt x 2 kk ----
    bf16x8 qb[4][2];
    auto loadQ = [&](int qb0) {
        #pragma unroll
        for (int nt = 0; nt < 4; ++nt) {
            const int qrow = qb0 + nt * 16 + l16;
            #pragma unroll
            for (int kk = 0; kk < 2; ++kk) {
                const float* s = Qg + (qrb + qrow) * DH + kk * 32 + quad * 8;
                float4 f0 = *(const float4*)(s);
                float4 f1 = *(const float4*)(s + 4);
                bf16x8 t;
                t[0]=(bf16)f0.x; t[1]=(bf16)f0.y; t[2]=(bf16)f0.z; t[3]=(bf16)f0.w;
                t[4]=(bf16)f1.x; t[5]=(bf16)f1.y; t[6]=(bf16)f1.z; t[7]=(bf16)f1.w;
                qb[nt][kk] = t;
            }
        }
    };
    loadQ(qbase);

    floatx4 oacc[4][4];
    #pragma unroll
    for (int mt = 0; mt < 4; ++mt)
        #pragma unroll
        for (int nt = 0; nt < 4; ++nt) oacc[mt][nt] = (floatx4){0.f,0.f,0.f,0.f};
    float lpart[4] = {0.f, 0.f, 0.f, 0.f};

    // K-frag: A[m=key=l16(+16mt)][k=d=quad*8+j(+32kk)] -> row k0+mt*16+l16, 16B @ d
    // V-frag: A[m=d=l16(+16mt)][k=key=quad*8+j]       -> row mt*16+l16,   16B @ k0
    auto loadKV = [&](int kt, bf16x8 (&kf)[4], bf16x8 (&vf)[4]) {
        const int k0 = kt * TKS;
        #pragma unroll
        for (int mt = 0; mt < 2; ++mt)
            #pragma unroll
            for (int kk = 0; kk < 2; ++kk)
                kf[mt * 2 + kk] = *(const bf16x8*)(Kbh + (size_t)(k0 + mt * 16 + l16) * DH + kk * 32 + quad * 8);
        #pragma unroll
        for (int mt = 0; mt < 4; ++mt)
            vf[mt] = *(const bf16x8*)(Vbh + (size_t)(mt * 16 + l16) * T_SEQ + k0 + quad * 8);
    };

    auto parkHeavy = [&]() {       // dump heavy partial to this wave's area
        bf16* a = smem + (wave - 1) * 4608;
        float* al = (float*)(a + 4096);
        #pragma unroll
        for (int f = 0; f < 16; ++f) {
            bf16x4 w;
            #pragma unroll
            for (int e = 0; e < 4; ++e) w[e] = (bf16)oacc[f >> 2][f & 3][e];
            *(bf16x4*)&a[(f * 64 + lane) * 4] = w;
        }
        #pragma unroll
        for (int nt = 0; nt < 4; ++nt) { al[nt * 64 + lane] = lpart[nt]; lpart[nt] = 0.f; }
        #pragma unroll
        for (int mt = 0; mt < 4; ++mt)
            #pragma unroll
            for (int nt = 0; nt < 4; ++nt) oacc[mt][nt] = (floatx4){0.f,0.f,0.f,0.f};
        hasPark = true;
        heavyNow = false;
        qbase = ql;
        loadQ(ql);
    };

    auto body = [&](int t, bf16x8 (&kc)[4], bf16x8 (&vc)[4],
                    bf16x8 (&kn)[4], bf16x8 (&vn)[4]) {
        if (heavyNow && t == B) parkHeavy();
        const int kt = (t < B) ? t : t - B;
        const int k0 = kt * TKS;
        const int tn = t + 1;
        if (tn < tw1) {                          // register prefetch for t+1
            const int ktn = (tn < B) ? tn : tn - B;
            loadKV(ktn, kn, vn);
        }
        // ---- S^T = K·Q^T + mask + exp + P-write, per key-subtile mt ----
        #pragma unroll
        for (int mt = 0; mt < 2; ++mt) {
            floatx4 sa[4];
            #pragma unroll
            for (int nt = 0; nt < 4; ++nt) sa[nt] = (floatx4){0.f,0.f,0.f,0.f};
            #pragma unroll
            for (int kk = 0; kk < 2; ++kk) {
                bf16x8 kf = kc[mt * 2 + kk];
                #pragma unroll
                for (int nt = 0; nt < 4; ++nt)
                    sa[nt] = __builtin_amdgcn_mfma_f32_16x16x32_bf16(kf, qb[nt][kk], sa[nt], 0, 0, 0);
            }
            if (k0 + TKS - 1 > qbase) {          // diagonal band only
                #pragma unroll
                for (int nt = 0; nt < 4; ++nt) {
                    const int qg = qbase + nt * 16 + l16;
                    #pragma unroll
                    for (int r = 0; r < 4; ++r) {
                        const int keyg = k0 + mt * 16 + quad * 4 + r;
                        if (keyg > qg) sa[nt][r] = -INFINITY;
                    }
                }
            }
            #pragma unroll
            for (int nt = 0; nt < 4; ++nt) {
                bf16x4 w;
                #pragma unroll
                for (int r = 0; r < 4; ++r) {
                    const float pv = __builtin_amdgcn_exp2f(CEXP * sa[nt][r]);
                    lpart[nt] += pv;
                    w[r] = (bf16)pv;
                }
                const int slot = (mt * 2 + (quad >> 1)) ^ psw;
                *(bf16x4*)&Pw[(nt * 16 + l16) * 32 + slot * 8 + (quad & 1) * 4] = w;
            }
        }
        // ---- P^T B-fragments (wave-private, in-order DS) ----
        bf16x8 pf[4];
        #pragma unroll
        for (int nt = 0; nt < 4; ++nt)
            pf[nt] = *(const bf16x8*)&Pw[(nt * 16 + l16) * 32 + ((quad ^ psw) * 8)];
        // ---- O^T += V^T·P^T (V-frags from regs) ----
        #pragma unroll
        for (int mt = 0; mt < 4; ++mt) {
            #pragma unroll
            for (int nt = 0; nt < 4; ++nt)
                oacc[mt][nt] = __builtin_amdgcn_mfma_f32_16x16x32_bf16(vc[mt], pf[nt], oacc[mt][nt], 0, 0, 0);
        }
    };

    bf16x8 kA[4], vA[4], kB[4], vB[4];
    loadKV((tw0 < B) ? tw0 : tw0 - B, kA, vA);

    int t = tw0;
    while (true) {
        body(t, kA, vA, kB, vB);
        if (++t == tw1) break;
        body(t, kB, vB, kA, vA);
        if (++t == tw1) break;
    }

    // ================= end combine (R10-proven, park-aware) =================
    __syncthreads();
    const bool hH = (tw0 < B);
    const bool hL = (tw1 > B);
    if (wave >= 1 && hH && !hasPark) {           // unparked heavy partials
        bf16* a = smem + (wave - 1) * 4608;
        float* al = (float*)(a + 4096);
        #pragma unroll
        for (int f = 0; f < 16; ++f) {
            bf16x4 w;
            #pragma unroll
            for (int e = 0; e < 4; ++e) w[e] = (bf16)oacc[f >> 2][f & 3][e];
            *(bf16x4*)&a[(f * 64 + lane) * 4] = w;
        }
        #pragma unroll
        for (int nt = 0; nt < 4; ++nt)
            al[nt * 64 + lane] = lpart[nt];
    }
    if (wave >= 2 && hL) {                       // light partials
        bf16* a = smem + (wave + 1) * 4608;      // wave2->area3, wave3->area4
        float* al = (float*)(a + 4096);
        #pragma unroll
        for (int f = 0; f < 16; ++f) {
            bf16x4 w;
            #pragma unroll
            for (int e = 0; e < 4; ++e) w[e] = (bf16)oacc[f >> 2][f & 3][e];
            *(bf16x4*)&a[(f * 64 + lane) * 4] = w;
        }
        #pragma unroll
        for (int nt = 0; nt < 4; ++nt)
            al[nt * 64 + lane] = lpart[nt];
    }
    __syncthreads();

    if (wave <= 1) {
        int qfin;
        if (wave == 0) {
            qfin = qh;
            const int nA = (B > 50) ? 3 : ((B > 34) ? 2 : 1);
            for (int i = 0; i < nA; ++i) {
                const bf16* a = smem + i * 4608;
                const float* al = (const float*)(a + 4096);
                #pragma unroll
                for (int f = 0; f < 16; ++f) {
                    bf16x4 w = *(const bf16x4*)&a[(f * 64 + lane) * 4];
                    #pragma unroll
                    for (int e = 0; e < 4; ++e) oacc[f >> 2][f & 3][e] += (float)w[e];
                }
                #pragma unroll
                for (int nt = 0; nt < 4; ++nt) lpart[nt] += al[nt * 64 + lane];
            }
        } else {
            qfin = ql;
            #pragma unroll
            for (int mt = 0; mt < 4; ++mt)
                #pragma unroll
                for (int nt = 0; nt < 4; ++nt) oacc[mt][nt] = (floatx4){0.f,0.f,0.f,0.f};
            #pragma unroll
            for (int nt = 0; nt < 4; ++nt) lpart[nt] = 0.f;
            const int i0 = (B < 50) ? 3 : 4;
            for (int i = i0; i <= 4; ++i) {
                const bf16* a = smem + i * 4608;
                const float* al = (const float*)(a + 4096);
                #pragma unroll
                for (int f = 0; f < 16; ++f) {
                    bf16x4 w = *(const bf16x4*)&a[(f * 64 + lane) * 4];
                    #pragma unroll
                    for (int e = 0; e < 4; ++e) oacc[f >> 2][f & 3][e] += (float)w[e];
                }
                #pragma unroll
                for (int nt = 0; nt < 4; ++nt) lpart[nt] += al[nt * 64 + lane];
            }
        }
        float invl[4];
        #pragma unroll
        for (int nt = 0; nt < 4; ++nt) {
            float v = lpart[nt];
            v += __shfl_xor(v, 16);
            v += __shfl_xor(v, 32);
            invl[nt] = 1.0f / v;
        }
        #pragma unroll
        for (int nt = 0; nt < 4; ++nt) {
            const size_t qrow = qrb + qfin + nt * 16 + l16;
            #pragma unroll
            for (int mt = 0; mt < 4; ++mt) {
                float4 o;
                o.x = oacc[mt][nt][0] * invl[nt];
                o.y = oacc[mt][nt][1] * invl[nt];
                o.z = oacc[mt][nt][2] * invl[nt];
                o.w = oacc[mt][nt][3] * invl[nt];
                *(float4*)&Og[qrow * DH + mt * 16 + quad * 4] = o;
            }
        }
    }
}

extern "C" void kernel_launch(void* const* d_in, const int* in_sizes, int n_in,
                              void* d_out, int out_size, void* d_ws, size_t ws_size,
                              hipStream_t stream) {
    const float* Q = (const float*)d_in[0];
    const float* K = (const float*)d_in[1];
    const float* V = (const float*)d_in[2];
    float* O = (float*)d_out;
    (void)in_sizes; (void)n_in; (void)out_size; (void)ws_size;

    const size_t nelem = (size_t)BHN * T_SEQ * DH;   // 4,194,304
    bf16* Kbf = (bf16*)d_ws;            // 8 MiB
    bf16* Vtb = Kbf + nelem;            // 8 MiB

    prep<<<dim3(1024), dim3(256), 0, stream>>>(K, V, Kbf, Vtb);
    fa_fwd<<<dim3(512), dim3(256), 0, stream>>>(Q, Kbf, Vtb, O);
}

// Round 12
// 122.355 us; speedup vs baseline: 1.0833x; 1.0833x over previous
//
#include <hip/hip_runtime.h>
#include <hip/hip_bf16.h>

// Causal attention, B=2 NH=16 T=2048 D=64, fp32 I/O.
// R12 = R10 (wave-private DMA staging, barrier-free k-loop, uniform
// strip-pairing, in-LDS end combine) + FULL one-step prefetch:
// K(t+1) AND V(t+1) both staged at step top, single s_waitcnt vmcnt(8)
// (tile t landed, tile t+1 in flight across the whole step). P round-trip
// overlays the current K buffer (K frag reads all precede P writes;
// same-wave DS is in-order). Per-wave LDS: K0,K1,V0,V1 = 16 KB.

typedef __bf16 bf16;
typedef __bf16 bf16x4 __attribute__((ext_vector_type(4)));
typedef __bf16 bf16x8 __attribute__((ext_vector_type(8)));
typedef float floatx4 __attribute__((ext_vector_type(4)));

#define T_SEQ 2048
#define DH 64
#define TKS 32
#define BHN 32
#define CEXP 0.18033688011112042f  // (1/sqrt(64)) * log2(e)

__device__ __forceinline__ void gload16(const bf16* g, bf16* l) {
    __builtin_amdgcn_global_load_lds(
        (const __attribute__((address_space(1))) void*)g,
        (__attribute__((address_space(3))) void*)l, 16, 0, 0);
}

// ---------------- fused prepass (unchanged, proven) ----------------
__global__ __launch_bounds__(256) void prep(const float* __restrict__ K,
                                            const float* __restrict__ V,
                                            bf16* __restrict__ Kb,
                                            bf16* __restrict__ Vt) {
    const int bid = (int)blockIdx.x;
    const int tid = (int)threadIdx.x;
    if (bid < 512) {
        size_t i = ((size_t)bid * 256 + tid) * 8;
        #pragma unroll
        for (int it = 0; it < 4; ++it) {
            float4 a = *(const float4*)(K + i + 0);
            float4 b = *(const float4*)(K + i + 4);
            bf16x8 o;
            o[0]=(bf16)a.x; o[1]=(bf16)a.y; o[2]=(bf16)a.z; o[3]=(bf16)a.w;
            o[4]=(bf16)b.x; o[5]=(bf16)b.y; o[6]=(bf16)b.z; o[7]=(bf16)b.w;
            *(bf16x8*)(Kb + i) = o;
            i += (size_t)512 * 256 * 8;
        }
        return;
    }
    __shared__ bf16 tile[2][64][72];
    const int vb = bid - 512;
    const int bh = vb & (BHN - 1);
    const int tp = (vb >> 5) * 128;
    #pragma unroll
    for (int tt = 0; tt < 2; ++tt) {
        const int r = tid >> 2;
        const int c = (tid & 3) * 16;
        const float* s = V + ((size_t)bh * T_SEQ + tp + tt * 64 + r) * DH + c;
        float4 f0 = *(const float4*)(s + 0);
        float4 f1 = *(const float4*)(s + 4);
        float4 f2 = *(const float4*)(s + 8);
        float4 f3 = *(const float4*)(s + 12);
        bf16x8 p0, p1;
        p0[0]=(bf16)f0.x; p0[1]=(bf16)f0.y; p0[2]=(bf16)f0.z; p0[3]=(bf16)f0.w;
        p0[4]=(bf16)f1.x; p0[5]=(bf16)f1.y; p0[6]=(bf16)f1.z; p0[7]=(bf16)f1.w;
        p1[0]=(bf16)f2.x; p1[1]=(bf16)f2.y; p1[2]=(bf16)f2.z; p1[3]=(bf16)f2.w;
        p1[4]=(bf16)f3.x; p1[5]=(bf16)f3.y; p1[6]=(bf16)f3.z; p1[7]=(bf16)f3.w;
        *(bf16x8*)&tile[tt][r][c + 0] = p0;
        *(bf16x8*)&tile[tt][r][c + 8] = p1;
    }
    __syncthreads();
    #pragma unroll
    for (int tt = 0; tt < 2; ++tt) {
        const int d   = tid >> 2;
        const int tch = (tid & 3) * 16;
        bf16x8 o0, o1;
        #pragma unroll
        for (int j = 0; j < 8; ++j) { o0[j] = tile[tt][tch + j][d]; o1[j] = tile[tt][tch + 8 + j][d]; }
        bf16* o = Vt + ((size_t)bh * DH + d) * T_SEQ + tp + tt * 64 + tch;
        *(bf16x8*)(o + 0) = o0;
        *(bf16x8*)(o + 8) = o1;
    }
}

// ---------------- main flash kernel ----------------
// Per-wave LDS (bf16 elems, 8192 = 16 KB): K0@0, K1@2048, V0@4096, V1@6144.
// K tile [32 key][64 d]: row = 8x16B chunks, slot c of row r = global chunk c^(r&7).
// V tile [64 d][32 k]: row = 4x16B chunks, slot c of row r = global chunk c^((r>>1)&3).
// P tile [64 q][32 k] overlays the CURRENT K buffer (reads precede writes).
// MFMA 16x16x32: A[m=l16][k=quad*8+j], B[k=quad*8+j][n=l16], C/D col=l16,row=quad*4+r.
__global__ __launch_bounds__(256, 2)
void fa_fwd(const float* __restrict__ Qg, const bf16* __restrict__ Kb,
            const bf16* __restrict__ Vt, float* __restrict__ Og)
{
    __shared__ __align__(16) bf16 smem[32768];   // 64 KB

    const int gid = (int)blockIdx.x;
    const int bh  = gid & (BHN - 1);
    const int m   = gid >> 5;                    // 0..15
    const int B   = 64 - 2 * m;                  // heavy tile count (>=34)
    const int qh  = (31 - m) * 64;
    const int ql  = m * 64;

    const int tid  = (int)threadIdx.x;
    const int wave = tid >> 6;
    const int lane = tid & 63;
    const int quad = lane >> 4;
    const int l16  = lane & 15;
    const int psw  = (l16 >> 1) & 3;

    const int tw0 = (wave < 2) ? wave * 17 : 34 + (wave - 2) * 16;
    const int tw1 = tw0 + ((wave < 2) ? 17 : 16);

    bf16* W = smem + wave * 8192;

    const bf16* Kbh = Kb + (size_t)bh * (T_SEQ * DH);
    const bf16* Vbh = Vt + (size_t)bh * (DH * T_SEQ);
    const size_t qrb = (size_t)bh * T_SEQ;

    // staging lane constants
    const int rl  = lane >> 3;
    const int kch = (lane & 7) ^ (rl & 7);
    const int vr  = lane >> 2;
    const int vch = (lane & 3) ^ ((lane >> 3) & 3);

    bool heavyNow = (tw0 < B);
    int  qbase    = heavyNow ? qh : ql;
    bool hasPark  = false;

    bf16x8 qb[4][2];
    auto loadQ = [&](int qb0) {
        #pragma unroll
        for (int nt = 0; nt < 4; ++nt) {
            const int qrow = qb0 + nt * 16 + l16;
            #pragma unroll
            for (int kk = 0; kk < 2; ++kk) {
                const float* s = Qg + (qrb + qrow) * DH + kk * 32 + quad * 8;
                float4 f0 = *(const float4*)(s);
                float4 f1 = *(const float4*)(s + 4);
                bf16x8 t;
                t[0]=(bf16)f0.x; t[1]=(bf16)f0.y; t[2]=(bf16)f0.z; t[3]=(bf16)f0.w;
                t[4]=(bf16)f1.x; t[5]=(bf16)f1.y; t[6]=(bf16)f1.z; t[7]=(bf16)f1.w;
                qb[nt][kk] = t;
            }
        }
    };
    loadQ(qbase);

    floatx4 oacc[4][4];
    #pragma unroll
    for (int mt = 0; mt < 4; ++mt)
        #pragma unroll
        for (int nt = 0; nt < 4; ++nt) oacc[mt][nt] = (floatx4){0.f,0.f,0.f,0.f};
    float lpart[4] = {0.f, 0.f, 0.f, 0.f};
    bf16x4 parked[16];
    #pragma unroll
    for (int f = 0; f < 16; ++f) parked[f] = (bf16x4){(bf16)0.f,(bf16)0.f,(bf16)0.f,(bf16)0.f};
    float lpark[4] = {0.f, 0.f, 0.f, 0.f};

    auto kTileOf = [&](int t) { return (t < B) ? t : (t - B); };

    auto stageK = [&](int kt, bf16* dst) {
        const bf16* kg = Kbh + (size_t)kt * TKS * DH;
        #pragma unroll
        for (int g = 0; g < 4; ++g)
            gload16(kg + (size_t)(g * 8 + rl) * DH + kch * 8, dst + g * 512);
    };
    auto stageV = [&](int kt, bf16* dst) {
        const bf16* vg = Vbh + kt * TKS;
        #pragma unroll
        for (int g = 0; g < 4; ++g)
            gload16(vg + (size_t)(g * 16 + vr) * T_SEQ + vch * 8, dst + g * 512);
    };

    stageK(kTileOf(tw0), W);
    stageV(kTileOf(tw0), W + 4096);

    for (int t = tw0; t < tw1; ++t) {
        if (heavyNow && t == B) {                // park heavy, switch to light
            #pragma unroll
            for (int f = 0; f < 16; ++f) {
                bf16x4 w;
                #pragma unroll
                for (int e = 0; e < 4; ++e) w[e] = (bf16)oacc[f >> 2][f & 3][e];
                parked[f] = w;
            }
            #pragma unroll
            for (int nt = 0; nt < 4; ++nt) { lpark[nt] = lpart[nt]; lpart[nt] = 0.f; }
            #pragma unroll
            for (int mt = 0; mt < 4; ++mt)
                #pragma unroll
                for (int nt = 0; nt < 4; ++nt) oacc[mt][nt] = (floatx4){0.f,0.f,0.f,0.f};
            hasPark = true;
            heavyNow = false;
            qbase = ql;
            loadQ(ql);
        }

        const int cur = (t - tw0) & 1;
        bf16* Kcur = W + cur * 2048;
        bf16* Vcur = W + 4096 + cur * 2048;
        bf16* Pw   = Kcur;                       // overlay (reads precede writes)
        const int kt = kTileOf(t);
        const int k0 = kt * TKS;

        const bool pf = (t + 1 < tw1);
        if (pf) {                                // full prefetch of tile t+1
            const int ktn = kTileOf(t + 1);
            stageK(ktn, W + (cur ^ 1) * 2048);
            stageV(ktn, W + 4096 + (cur ^ 1) * 2048);
            __builtin_amdgcn_s_waitcnt(0x0F78);  // vmcnt(8): t landed, t+1 in flight
        } else {
            __builtin_amdgcn_s_waitcnt(0x0F70);  // vmcnt(0): last tile landed
        }

        // ---- S^T = K·Q^T (ALL K frag reads before any P write) ----
        floatx4 sa[2][4];
        #pragma unroll
        for (int mt = 0; mt < 2; ++mt)
            #pragma unroll
            for (int nt = 0; nt < 4; ++nt) sa[mt][nt] = (floatx4){0.f,0.f,0.f,0.f};
        #pragma unroll
        for (int kk = 0; kk < 2; ++kk) {
            #pragma unroll
            for (int mt = 0; mt < 2; ++mt) {
                bf16x8 kf = *(const bf16x8*)&Kcur[(mt * 16 + l16) * 64 + (((kk * 4 + quad) ^ (l16 & 7)) * 8)];
                #pragma unroll
                for (int nt = 0; nt < 4; ++nt)
                    sa[mt][nt] = __builtin_amdgcn_mfma_f32_16x16x32_bf16(kf, qb[nt][kk], sa[mt][nt], 0, 0, 0);
            }
        }
        // ---- causal mask (diagonal band) ----
        if (k0 + TKS - 1 > qbase) {
            #pragma unroll
            for (int mt = 0; mt < 2; ++mt)
                #pragma unroll
                for (int nt = 0; nt < 4; ++nt) {
                    const int qg = qbase + nt * 16 + l16;
                    #pragma unroll
                    for (int r = 0; r < 4; ++r) {
                        const int keyg = k0 + mt * 16 + quad * 4 + r;
                        if (keyg > qg) sa[mt][nt][r] = -INFINITY;
                    }
                }
        }
        // ---- exp2 + P writes (into Kcur overlay) ----
        #pragma unroll
        for (int mt = 0; mt < 2; ++mt)
            #pragma unroll
            for (int nt = 0; nt < 4; ++nt) {
                bf16x4 w;
                #pragma unroll
                for (int r = 0; r < 4; ++r) {
                    const float pv = __builtin_amdgcn_exp2f(CEXP * sa[mt][nt][r]);
                    lpart[nt] += pv;
                    w[r] = (bf16)pv;
                }
                const int slot = (mt * 2 + (quad >> 1)) ^ psw;
                *(bf16x4*)&Pw[(nt * 16 + l16) * 32 + slot * 8 + (quad & 1) * 4] = w;
            }
        // ---- P^T B-fragments ----
        bf16x8 pfr[4];
        #pragma unroll
        for (int nt = 0; nt < 4; ++nt)
            pfr[nt] = *(const bf16x8*)&Pw[(nt * 16 + l16) * 32 + ((quad ^ psw) * 8)];
        // ---- O^T += V^T·P^T ----
        #pragma unroll
        for (int mt = 0; mt < 4; ++mt) {
            bf16x8 vf = *(const bf16x8*)&Vcur[(mt * 16 + l16) * 32 + ((quad ^ psw) * 8)];
            #pragma unroll
            for (int nt = 0; nt < 4; ++nt)
                oacc[mt][nt] = __builtin_amdgcn_mfma_f32_16x16x32_bf16(vf, pfr[nt], oacc[mt][nt], 0, 0, 0);
        }
    }

    // ================= end combine (R10-proven) =================
    __syncthreads();
    const bool hH = (tw0 < B);
    const bool hL = (tw1 > B);
    if (wave >= 1 && hH) {
        bf16* a = smem + (wave - 1) * 4608;
        float* al = (float*)(a + 4096);
        #pragma unroll
        for (int f = 0; f < 16; ++f) {
            bf16x4 w;
            if (hasPark) w = parked[f];
            else {
                #pragma unroll
                for (int e = 0; e < 4; ++e) w[e] = (bf16)oacc[f >> 2][f & 3][e];
            }
            *(bf16x4*)&a[(f * 64 + lane) * 4] = w;
        }
        #pragma unroll
        for (int nt = 0; nt < 4; ++nt)
            al[nt * 64 + lane] = hasPark ? lpark[nt] : lpart[nt];
    }
    if (wave >= 2 && hL) {
        bf16* a = smem + (wave + 1) * 4608;      // wave2->area3, wave3->area4
        float* al = (float*)(a + 4096);
        #pragma unroll
        for (int f = 0; f < 16; ++f) {
            bf16x4 w;
            #pragma unroll
            for (int e = 0; e < 4; ++e) w[e] = (bf16)oacc[f >> 2][f & 3][e];
            *(bf16x4*)&a[(f * 64 + lane) * 4] = w;
        }
        #pragma unroll
        for (int nt = 0; nt < 4; ++nt)
            al[nt * 64 + lane] = lpart[nt];
    }
    __syncthreads();

    if (wave <= 1) {
        int qfin;
        if (wave == 0) {
            qfin = qh;
            const int nA = (B > 50) ? 3 : ((B > 34) ? 2 : 1);
            for (int i = 0; i < nA; ++i) {
                const bf16* a = smem + i * 4608;
                const float* al = (const float*)(a + 4096);
                #pragma unroll
                for (int f = 0; f < 16; ++f) {
                    bf16x4 w = *(const bf16x4*)&a[(f * 64 + lane) * 4];
                    #pragma unroll
                    for (int e = 0; e < 4; ++e) oacc[f >> 2][f & 3][e] += (float)w[e];
                }
                #pragma unroll
                for (int nt = 0; nt < 4; ++nt) lpart[nt] += al[nt * 64 + lane];
            }
        } else {
            qfin = ql;
            #pragma unroll
            for (int mt = 0; mt < 4; ++mt)
                #pragma unroll
                for (int nt = 0; nt < 4; ++nt) oacc[mt][nt] = (floatx4){0.f,0.f,0.f,0.f};
            #pragma unroll
            for (int nt = 0; nt < 4; ++nt) lpart[nt] = 0.f;
            const int i0 = (B < 50) ? 3 : 4;
            for (int i = i0; i <= 4; ++i) {
                const bf16* a = smem + i * 4608;
                const float* al = (const float*)(a + 4096);
                #pragma unroll
                for (int f = 0; f < 16; ++f) {
                    bf16x4 w = *(const bf16x4*)&a[(f * 64 + lane) * 4];
                    #pragma unroll
                    for (int e = 0; e < 4; ++e) oacc[f >> 2][f & 3][e] += (float)w[e];
                }
                #pragma unroll
                for (int nt = 0; nt < 4; ++nt) lpart[nt] += al[nt * 64 + lane];
            }
        }
        float invl[4];
        #pragma unroll
        for (int nt = 0; nt < 4; ++nt) {
            float v = lpart[nt];
            v += __shfl_xor(v, 16);
            v += __shfl_xor(v, 32);
            invl[nt] = 1.0f / v;
        }
        #pragma unroll
        for (int nt = 0; nt < 4; ++nt) {
            const size_t qrow = qrb + qfin + nt * 16 + l16;
            #pragma unroll
            for (int mt = 0; mt < 4; ++mt) {
                float4 o;
                o.x = oacc[mt][nt][0] * invl[nt];
                o.y = oacc[mt][nt][1] * invl[nt];
                o.z = oacc[mt][nt][2] * invl[nt];
                o.w = oacc[mt][nt][3] * invl[nt];
                *(float4*)&Og[qrow * DH + mt * 16 + quad * 4] = o;
            }
        }
    }
}

extern "C" void kernel_launch(void* const* d_in, const int* in_sizes, int n_in,
                              void* d_out, int out_size, void* d_ws, size_t ws_size,
                              hipStream_t stream) {
    const float* Q = (const float*)d_in[0];
    const float* K = (const float*)d_in[1];
    const float* V = (const float*)d_in[2];
    float* O = (float*)d_out;
    (void)in_sizes; (void)n_in; (void)out_size; (void)ws_size;

    const size_t nelem = (size_t)BHN * T_SEQ * DH;   // 4,194,304
    bf16* Kbf = (bf16*)d_ws;            // 8 MiB
    bf16* Vtb = Kbf + nelem;            // 8 MiB

    prep<<<dim3(1024), dim3(256), 0, stream>>>(K, V, Kbf, Vtb);
    fa_fwd<<<dim3(512), dim3(256), 0, stream>>>(Q, Kbf, Vtb, O);
}